// Round 2
// baseline (495.792 us; speedup 1.0000x reference)
//
#include <hip/hip_runtime.h>
#include <math.h>

#define N_NODES 100000
#define N_EDGES 1600000
#define NB_BANK 1000
#define N_PAIRS 500000

struct Consts {
  float C[27*8];    // [P1|P2] : X -> 8 channels
  float Rb[27*8];   // [Wb@Ttop | Wb@Tbot]
  float u[8];       // [b1@W2@Ttop | b1@W2@Tbot]  (coefficient of d_i)
  float vg[8];      // [b2@Ttop + c | b2@Tbot]
  float vb[8];      // [bb@Ttop + c | bb@Tbot]
};

// ---------------- tiny dense precompute (all weight-chain products) ----------
__global__ __launch_bounds__(256) void k_precompute(
    const float* __restrict__ W1, const float* __restrict__ b1,
    const float* __restrict__ W2, const float* __restrict__ b2,
    const float* __restrict__ Wb, const float* __restrict__ bb,
    const float* __restrict__ Wf1, const float* __restrict__ bf1,
    const float* __restrict__ Wf2, const float* __restrict__ bf2,
    const float* __restrict__ Wf3, const float* __restrict__ bf3,
    Consts* __restrict__ cst) {
  __shared__ float A[40*4];    // Wf2 @ Wf3
  __shared__ float T[100*4];   // Wf1 @ A
  __shared__ float B[60*8];    // W2 @ [Ttop|Tbot]
  __shared__ float cvec[4];
  const int tid = threadIdx.x;

  for (int idx = tid; idx < 160; idx += 256) {
    int r = idx >> 2, k = idx & 3;
    float s = 0.f;
    for (int j = 0; j < 20; ++j) s += Wf2[r*20+j] * Wf3[j*4+k];
    A[idx] = s;
  }
  __syncthreads();
  for (int idx = tid; idx < 400; idx += 256) {
    int r = idx >> 2, k = idx & 3;
    float s = 0.f;
    for (int j = 0; j < 40; ++j) s += Wf1[r*40+j] * A[j*4+k];
    T[idx] = s;
  }
  if (tid < 4) {
    float s = bf3[tid];
    for (int j = 0; j < 40; ++j) s += bf1[j] * A[j*4+tid];
    for (int j = 0; j < 20; ++j) s += bf2[j] * Wf3[j*4+tid];
    cvec[tid] = s;
  }
  __syncthreads();
  for (int idx = tid; idx < 480; idx += 256) {
    int r = idx >> 3, k = idx & 7;
    int half = k >> 2, kk = k & 3;
    float s = 0.f;
    for (int j = 0; j < 50; ++j) s += W2[r*50+j] * T[(half*50+j)*4+kk];
    B[idx] = s;
  }
  __syncthreads();
  for (int idx = tid; idx < 456; idx += 256) {
    if (idx < 216) {                       // C = W1 @ B [27,8]
      int r = idx >> 3, k = idx & 7;
      float s = 0.f;
      for (int j = 0; j < 60; ++j) s += W1[r*60+j] * B[j*8+k];
      cst->C[idx] = s;
    } else if (idx < 432) {                // Rb = Wb @ [Ttop|Tbot] [27,8]
      int i2 = idx - 216;
      int r = i2 >> 3, k = i2 & 7, half = k >> 2, kk = k & 3;
      float s = 0.f;
      for (int j = 0; j < 50; ++j) s += Wb[r*50+j] * T[(half*50+j)*4+kk];
      cst->Rb[i2] = s;
    } else if (idx < 440) {                // u = b1 @ B
      int k = idx - 432;
      float s = 0.f;
      for (int j = 0; j < 60; ++j) s += b1[j] * B[j*8+k];
      cst->u[k] = s;
    } else if (idx < 448) {                // vg = b2 @ [Ttop|Tbot] (+c on half 0)
      int k = idx - 440, half = k >> 2, kk = k & 3;
      float s = (half == 0) ? cvec[kk] : 0.f;
      for (int j = 0; j < 50; ++j) s += b2[j] * T[(half*50+j)*4+kk];
      cst->vg[k] = s;
    } else {                               // vb = bb @ [Ttop|Tbot] (+c on half 0)
      int k = idx - 448, half = k >> 2, kk = k & 3;
      float s = (half == 0) ? cvec[kk] : 0.f;
      for (int j = 0; j < 50; ++j) s += bb[j] * T[(half*50+j)*4+kk];
      cst->vb[k] = s;
    }
  }
}

// ---------------- degree / dinv ----------------
__global__ __launch_bounds__(256) void k_deg(const int* __restrict__ ei,
                                             int* __restrict__ deg) {
  int e = blockIdx.x * 256 + threadIdx.x;
  if (e < N_EDGES) atomicAdd(&deg[ei[N_EDGES + e]], 1);
}

__global__ __launch_bounds__(256) void k_dinv(const int* __restrict__ deg,
                                              float* __restrict__ dinv) {
  int i = blockIdx.x * 256 + threadIdx.x;
  if (i < N_NODES) dinv[i] = rsqrtf((float)deg[i] + 1.0f);  // +1 self-loop
}

// ---------------- X8 = X @ [P1|P2]  ----------------
__global__ __launch_bounds__(256) void k_x8(const float* __restrict__ x,
                                            const Consts* __restrict__ cst,
                                            float* __restrict__ X8) {
  __shared__ float xs[32*27];
  const int tid = threadIdx.x;
  const int base = blockIdx.x * 32 * 27;
  for (int j = tid; j < 32*27; j += 256) {
    int g = base + j;
    xs[j] = (g < N_NODES*27) ? x[g] : 0.f;
  }
  __syncthreads();
  int li = tid >> 3, k = tid & 7;
  int node = blockIdx.x * 32 + li;
  if (node < N_NODES) {
    float s = 0.f;
    for (int c = 0; c < 27; ++c) s += xs[li*27+c] * cst->C[c*8+k];
    X8[node*8+k] = s;
  }
}

// ---------------- self-loop init: dst = dinv^2 * src (per node), opt dvec ----
__global__ __launch_bounds__(256) void k_selfinit(const float* __restrict__ src,
                                                  const float* __restrict__ dinv,
                                                  float* __restrict__ dst,
                                                  float* __restrict__ dvec) {
  int i = blockIdx.x * 256 + threadIdx.x;
  if (i < N_NODES) {
    float nn = dinv[i] * dinv[i];
    const float4* s4 = (const float4*)(src + i*8);
    float4 a = s4[0], b = s4[1];
    a.x *= nn; a.y *= nn; a.z *= nn; a.w *= nn;
    b.x *= nn; b.y *= nn; b.z *= nn; b.w *= nn;
    float4* d4 = (float4*)(dst + i*8);
    d4[0] = a; d4[1] = b;
    if (dvec) dvec[i] = nn;
  }
}

// ---------------- edge scatter: dst[d] += norm * src[s], lane per (edge,ch) --
__global__ __launch_bounds__(256) void k_scatter(const int* __restrict__ ei,
                                                 const float* __restrict__ dinv,
                                                 const float* __restrict__ src_feat,
                                                 float* __restrict__ dst_feat,
                                                 float* __restrict__ dvec) {
  int t = blockIdx.x * 256 + threadIdx.x;
  int e = t >> 3, c = t & 7;
  if (e < N_EDGES) {
    int s = ei[e], d = ei[N_EDGES + e];
    float nrm = dinv[s] * dinv[d];
    atomicAdd(&dst_feat[d*8 + c], nrm * src_feat[s*8 + c]);
    if (dvec && c == 0) atomicAdd(&dvec[d], nrm);
  }
}

// ---------------- per-node finalize + bank path -> gall [(N+NB),8] ----------
__global__ __launch_bounds__(256) void k_gall(const float* __restrict__ G,
                                              const float* __restrict__ dvec,
                                              const float* __restrict__ bank,
                                              const Consts* __restrict__ cst,
                                              float* __restrict__ gall) {
  int t = blockIdx.x * 256 + threadIdx.x;
  int i = t >> 3, k = t & 7;
  if (i < N_NODES) {
    gall[t] = G[t] + dvec[i] * cst->u[k] + cst->vg[k];
  } else if (i < N_NODES + NB_BANK) {
    int b = i - N_NODES;
    float s = cst->vb[k];
    for (int c = 0; c < 27; ++c) s += bank[b*27+c] * cst->Rb[c*8+k];
    gall[t] = s;
  }
}

// ---------------- float <-> monotone-key helpers for atomic max -------------
__device__ inline unsigned int f2key(float f) {
  int b = __float_as_int(f);
  return (b >= 0) ? ((unsigned)b | 0x80000000u) : ~(unsigned)b;
}
__device__ inline float key2f(unsigned int key) {
  unsigned ub = (key & 0x80000000u) ? (key ^ 0x80000000u) : ~key;
  return __int_as_float((int)ub);
}

// ---------------- pair gather + z + column max -------------------------------
__global__ __launch_bounds__(256) void k_z(const int* __restrict__ node1,
                                           const int* __restrict__ node2,
                                           const float* __restrict__ gall,
                                           float* __restrict__ z,
                                           unsigned int* __restrict__ maxkeys) {
  int p = blockIdx.x * 256 + threadIdx.x;
  float4 zv = make_float4(-1e30f, -1e30f, -1e30f, -1e30f);
  if (p < N_PAIRS) {
    int n1 = node1[p], n2 = node2[p];
    const float4 a = *(const float4*)(gall + n1*8);
    const float4 b = *(const float4*)(gall + n2*8 + 4);
    zv = make_float4(a.x+b.x, a.y+b.y, a.z+b.z, a.w+b.w);
    ((float4*)z)[p] = zv;
  }
  __shared__ float4 sm[256];
  sm[threadIdx.x] = zv;
  __syncthreads();
  for (int s = 128; s > 0; s >>= 1) {
    if (threadIdx.x < s) {
      float4 o = sm[threadIdx.x + s];
      float4 m = sm[threadIdx.x];
      m.x = fmaxf(m.x, o.x); m.y = fmaxf(m.y, o.y);
      m.z = fmaxf(m.z, o.z); m.w = fmaxf(m.w, o.w);
      sm[threadIdx.x] = m;
    }
    __syncthreads();
  }
  if (threadIdx.x < 4) {
    float4 m = sm[0];
    float v = (threadIdx.x == 0) ? m.x : (threadIdx.x == 1) ? m.y
             : (threadIdx.x == 2) ? m.z : m.w;
    atomicMax(&maxkeys[threadIdx.x], f2key(v));
  }
}

// ---------------- sum of exp(z - m) per column -------------------------------
__global__ __launch_bounds__(256) void k_sumexp(const float* __restrict__ z,
                                                const unsigned int* __restrict__ maxkeys,
                                                float* __restrict__ sums) {
  int p = blockIdx.x * 256 + threadIdx.x;
  float m0 = key2f(maxkeys[0]), m1 = key2f(maxkeys[1]);
  float m2 = key2f(maxkeys[2]), m3 = key2f(maxkeys[3]);
  float4 acc = make_float4(0.f, 0.f, 0.f, 0.f);
  if (p < N_PAIRS) {
    float4 zv = ((const float4*)z)[p];
    acc.x = expf(zv.x - m0); acc.y = expf(zv.y - m1);
    acc.z = expf(zv.z - m2); acc.w = expf(zv.w - m3);
  }
  __shared__ float4 sm[256];
  sm[threadIdx.x] = acc;
  __syncthreads();
  for (int s = 128; s > 0; s >>= 1) {
    if (threadIdx.x < s) {
      float4 o = sm[threadIdx.x + s];
      float4 m = sm[threadIdx.x];
      m.x += o.x; m.y += o.y; m.z += o.z; m.w += o.w;
      sm[threadIdx.x] = m;
    }
    __syncthreads();
  }
  if (threadIdx.x < 4) {
    float4 m = sm[0];
    float v = (threadIdx.x == 0) ? m.x : (threadIdx.x == 1) ? m.y
             : (threadIdx.x == 2) ? m.z : m.w;
    atomicAdd(&sums[threadIdx.x], v);
  }
}

// ---------------- normalize --------------------------------------------------
__global__ __launch_bounds__(256) void k_final(const float* __restrict__ z,
                                               const unsigned int* __restrict__ maxkeys,
                                               const float* __restrict__ sums,
                                               float* __restrict__ out) {
  int p = blockIdx.x * 256 + threadIdx.x;
  if (p < N_PAIRS) {
    float m0 = key2f(maxkeys[0]), m1 = key2f(maxkeys[1]);
    float m2 = key2f(maxkeys[2]), m3 = key2f(maxkeys[3]);
    float i0 = 1.f / sums[0], i1 = 1.f / sums[1];
    float i2 = 1.f / sums[2], i3 = 1.f / sums[3];
    float4 zv = ((const float4*)z)[p];
    float4 o = make_float4(expf(zv.x - m0) * i0, expf(zv.y - m1) * i1,
                           expf(zv.z - m2) * i2, expf(zv.w - m3) * i3);
    ((float4*)out)[p] = o;
  }
}

extern "C" void kernel_launch(void* const* d_in, const int* in_sizes, int n_in,
                              void* d_out, int out_size, void* d_ws, size_t ws_size,
                              hipStream_t stream) {
  const float* x    = (const float*)d_in[0];
  const float* bank = (const float*)d_in[1];
  const float* W1   = (const float*)d_in[2];
  const float* b1   = (const float*)d_in[3];
  const float* W2   = (const float*)d_in[4];
  const float* b2   = (const float*)d_in[5];
  const float* Wb   = (const float*)d_in[6];
  const float* bb   = (const float*)d_in[7];
  const float* Wf1  = (const float*)d_in[8];
  const float* bf1  = (const float*)d_in[9];
  const float* Wf2  = (const float*)d_in[10];
  const float* bf2  = (const float*)d_in[11];
  const float* Wf3  = (const float*)d_in[12];
  const float* bf3  = (const float*)d_in[13];
  const int* ei     = (const int*)d_in[14];
  const int* node1  = (const int*)d_in[15];
  const int* node2  = (const int*)d_in[16];
  float* out = (float*)d_out;

  char* w = (char*)d_ws;
  size_t off = 0;
  auto take = [&](size_t bytes) -> char* {
    char* p = w + off;
    off = (off + bytes + 255) & ~(size_t)255;
    return p;
  };
  Consts* cst   = (Consts*)take(sizeof(Consts));
  int*    deg   = (int*)take(N_NODES * 4);
  float*  dinv  = (float*)take(N_NODES * 4);
  float*  X8    = (float*)take((size_t)N_NODES * 8 * 4);
  float*  Y8    = (float*)take((size_t)N_NODES * 8 * 4);
  float*  dvec  = (float*)take(N_NODES * 4);
  float*  G     = (float*)take((size_t)N_NODES * 8 * 4);
  float*  gall  = (float*)take((size_t)(N_NODES + NB_BANK) * 8 * 4);
  float*  z     = (float*)take((size_t)N_PAIRS * 4 * 4);
  unsigned int* maxkeys = (unsigned int*)take(16);
  float*  sums  = (float*)take(16);

  hipMemsetAsync(deg, 0, N_NODES * 4, stream);
  hipMemsetAsync(maxkeys, 0, 16, stream);
  hipMemsetAsync(sums, 0, 16, stream);

  k_precompute<<<1, 256, 0, stream>>>(W1, b1, W2, b2, Wb, bb,
                                      Wf1, bf1, Wf2, bf2, Wf3, bf3, cst);
  k_deg<<<(N_EDGES + 255) / 256, 256, 0, stream>>>(ei, deg);
  k_dinv<<<(N_NODES + 255) / 256, 256, 0, stream>>>(deg, dinv);
  k_x8<<<(N_NODES + 31) / 32, 256, 0, stream>>>(x, cst, X8);
  // pass 1: Y8 = Â [X8], dvec = Â 1
  k_selfinit<<<(N_NODES + 255) / 256, 256, 0, stream>>>(X8, dinv, Y8, dvec);
  k_scatter<<<(N_EDGES * 8) / 256, 256, 0, stream>>>(ei, dinv, X8, Y8, dvec);
  // pass 2: G = Â Y8
  k_selfinit<<<(N_NODES + 255) / 256, 256, 0, stream>>>(Y8, dinv, G, nullptr);
  k_scatter<<<(N_EDGES * 8) / 256, 256, 0, stream>>>(ei, dinv, Y8, G, nullptr);

  k_gall<<<((N_NODES + NB_BANK) * 8 + 255) / 256, 256, 0, stream>>>(G, dvec, bank, cst, gall);
  k_z<<<(N_PAIRS + 255) / 256, 256, 0, stream>>>(node1, node2, gall, z, maxkeys);
  k_sumexp<<<(N_PAIRS + 255) / 256, 256, 0, stream>>>(z, maxkeys, sums);
  k_final<<<(N_PAIRS + 255) / 256, 256, 0, stream>>>(z, maxkeys, sums, out);
}

// Round 3
// 431.564 us; speedup vs baseline: 1.1488x; 1.1488x over previous
//
#include <hip/hip_runtime.h>
#include <math.h>

#define N_NODES 100000
#define N_EDGES 1600000
#define NB_BANK 1000
#define N_PAIRS 500000
#define NBLK 391   // ceil(N_NODES/256)

struct Consts {
  float C[27*8];    // [P1|P2] : X -> 8 channels
  float Rb[27*8];   // [Wb@Ttop | Wb@Tbot]
  float u[8];       // [b1@W2@Ttop | b1@W2@Tbot]  (coefficient of dvec_i)
  float vg[8];      // [b2@Ttop + c | b2@Tbot]
  float vb[8];      // [bb@Ttop + c | bb@Tbot]
};

// ---------------- tiny dense precompute (all weight-chain products) ----------
__global__ __launch_bounds__(256) void k_precompute(
    const float* __restrict__ W1, const float* __restrict__ b1,
    const float* __restrict__ W2, const float* __restrict__ b2,
    const float* __restrict__ Wb, const float* __restrict__ bb,
    const float* __restrict__ Wf1, const float* __restrict__ bf1,
    const float* __restrict__ Wf2, const float* __restrict__ bf2,
    const float* __restrict__ Wf3, const float* __restrict__ bf3,
    Consts* __restrict__ cst) {
  __shared__ float A[40*4];    // Wf2 @ Wf3
  __shared__ float T[100*4];   // Wf1 @ A
  __shared__ float B[60*8];    // W2 @ [Ttop|Tbot]
  __shared__ float cvec[4];
  const int tid = threadIdx.x;

  for (int idx = tid; idx < 160; idx += 256) {
    int r = idx >> 2, k = idx & 3;
    float s = 0.f;
    for (int j = 0; j < 20; ++j) s += Wf2[r*20+j] * Wf3[j*4+k];
    A[idx] = s;
  }
  __syncthreads();
  for (int idx = tid; idx < 400; idx += 256) {
    int r = idx >> 2, k = idx & 3;
    float s = 0.f;
    for (int j = 0; j < 40; ++j) s += Wf1[r*40+j] * A[j*4+k];
    T[idx] = s;
  }
  if (tid < 4) {
    float s = bf3[tid];
    for (int j = 0; j < 40; ++j) s += bf1[j] * A[j*4+tid];
    for (int j = 0; j < 20; ++j) s += bf2[j] * Wf3[j*4+tid];
    cvec[tid] = s;
  }
  __syncthreads();
  for (int idx = tid; idx < 480; idx += 256) {
    int r = idx >> 3, k = idx & 7;
    int half = k >> 2, kk = k & 3;
    float s = 0.f;
    for (int j = 0; j < 50; ++j) s += W2[r*50+j] * T[(half*50+j)*4+kk];
    B[idx] = s;
  }
  __syncthreads();
  for (int idx = tid; idx < 456; idx += 256) {
    if (idx < 216) {                       // C = W1 @ B [27,8]
      int r = idx >> 3, k = idx & 7;
      float s = 0.f;
      for (int j = 0; j < 60; ++j) s += W1[r*60+j] * B[j*8+k];
      cst->C[idx] = s;
    } else if (idx < 432) {                // Rb = Wb @ [Ttop|Tbot] [27,8]
      int i2 = idx - 216;
      int r = i2 >> 3, k = i2 & 7, half = k >> 2, kk = k & 3;
      float s = 0.f;
      for (int j = 0; j < 50; ++j) s += Wb[r*50+j] * T[(half*50+j)*4+kk];
      cst->Rb[i2] = s;
    } else if (idx < 440) {                // u = b1 @ B
      int k = idx - 432;
      float s = 0.f;
      for (int j = 0; j < 60; ++j) s += b1[j] * B[j*8+k];
      cst->u[k] = s;
    } else if (idx < 448) {                // vg = b2 @ [Ttop|Tbot] (+c on half 0)
      int k = idx - 440, half = k >> 2, kk = k & 3;
      float s = (half == 0) ? cvec[kk] : 0.f;
      for (int j = 0; j < 50; ++j) s += b2[j] * T[(half*50+j)*4+kk];
      cst->vg[k] = s;
    } else {                               // vb = bb @ [Ttop|Tbot] (+c on half 0)
      int k = idx - 448, half = k >> 2, kk = k & 3;
      float s = (half == 0) ? cvec[kk] : 0.f;
      for (int j = 0; j < 50; ++j) s += bb[j] * T[(half*50+j)*4+kk];
      cst->vb[k] = s;
    }
  }
}

// ---------------- degree / dinv ----------------
__global__ __launch_bounds__(256) void k_deg(const int* __restrict__ ei,
                                             int* __restrict__ deg) {
  int e = blockIdx.x * 256 + threadIdx.x;
  if (e < N_EDGES) atomicAdd(&deg[ei[N_EDGES + e]], 1);
}

__global__ __launch_bounds__(256) void k_dinv(const int* __restrict__ deg,
                                              float* __restrict__ dinv) {
  int i = blockIdx.x * 256 + threadIdx.x;
  if (i < N_NODES) dinv[i] = rsqrtf((float)deg[i] + 1.0f);  // +1 self-loop
}

// ---------------- exclusive scan of deg -> rowptr, cursor --------------------
__global__ __launch_bounds__(256) void k_scan1(const int* __restrict__ deg,
                                               int* __restrict__ blocksum) {
  __shared__ int sm[256];
  int i = blockIdx.x * 256 + threadIdx.x;
  sm[threadIdx.x] = (i < N_NODES) ? deg[i] : 0;
  __syncthreads();
  for (int s = 128; s > 0; s >>= 1) {
    if (threadIdx.x < s) sm[threadIdx.x] += sm[threadIdx.x + s];
    __syncthreads();
  }
  if (threadIdx.x == 0) blocksum[blockIdx.x] = sm[0];
}

__global__ __launch_bounds__(512) void k_scan2(const int* __restrict__ blocksum,
                                               int* __restrict__ blockoff) {
  __shared__ int sm[512];
  int t = threadIdx.x;
  int v = (t < NBLK) ? blocksum[t] : 0;
  sm[t] = v;
  __syncthreads();
  for (int off = 1; off < 512; off <<= 1) {
    int u = (t >= off) ? sm[t - off] : 0;
    __syncthreads();
    sm[t] += u;
    __syncthreads();
  }
  if (t < NBLK) blockoff[t] = sm[t] - v;  // exclusive
}

__global__ __launch_bounds__(256) void k_scan3(const int* __restrict__ deg,
                                               const int* __restrict__ blockoff,
                                               int* __restrict__ rowptr,
                                               int* __restrict__ cursor) {
  __shared__ int sm[256];
  int i = blockIdx.x * 256 + threadIdx.x;
  int t = threadIdx.x;
  int v = (i < N_NODES) ? deg[i] : 0;
  sm[t] = v;
  __syncthreads();
  for (int off = 1; off < 256; off <<= 1) {
    int u = (t >= off) ? sm[t - off] : 0;
    __syncthreads();
    sm[t] += u;
    __syncthreads();
  }
  if (i < N_NODES) {
    int excl = blockoff[blockIdx.x] + sm[t] - v;
    rowptr[i] = excl;
    cursor[i] = excl;
  }
  if (i == 0) rowptr[N_NODES] = N_EDGES;
}

// ---------------- CSR fill: csr_src[slot(d)] = s -----------------------------
__global__ __launch_bounds__(256) void k_fill(const int* __restrict__ ei,
                                              int* __restrict__ cursor,
                                              int* __restrict__ csr_src) {
  int e = blockIdx.x * 256 + threadIdx.x;
  if (e < N_EDGES) {
    int s = ei[e], d = ei[N_EDGES + e];
    int pos = atomicAdd(&cursor[d], 1);
    csr_src[pos] = s;
  }
}

// ---------------- Xs = (X @ [P1|P2]) * dinv[i]  ------------------------------
__global__ __launch_bounds__(256) void k_x8(const float* __restrict__ x,
                                            const float* __restrict__ dinv,
                                            const Consts* __restrict__ cst,
                                            float* __restrict__ Xs) {
  __shared__ float xs[32*27];
  const int tid = threadIdx.x;
  const int base = blockIdx.x * 32 * 27;
  for (int j = tid; j < 32*27; j += 256) {
    int g = base + j;
    xs[j] = (g < N_NODES*27) ? x[g] : 0.f;
  }
  __syncthreads();
  int li = tid >> 3, k = tid & 7;
  int node = blockIdx.x * 32 + li;
  if (node < N_NODES) {
    float s = 0.f;
    for (int c = 0; c < 27; ++c) s += xs[li*27+c] * cst->C[c*8+k];
    Xs[node*8+k] = s * dinv[node];
  }
}

// ---------------- gather pass 1: Ys = n^2 (sum_in Xs + Xs_self), dvec --------
__global__ __launch_bounds__(256) void k_gather1(const int* __restrict__ rowptr,
                                                 const int* __restrict__ csr_src,
                                                 const float* __restrict__ dinv,
                                                 const float* __restrict__ Xs,
                                                 float* __restrict__ Ys,
                                                 float* __restrict__ dvec) {
  int t = blockIdx.x * 256 + threadIdx.x;
  int d = t >> 3, c = t & 7;
  if (d >= N_NODES) return;
  int beg = rowptr[d], end = rowptr[d + 1];
  float nd = dinv[d];
  float acc = Xs[d*8 + c];          // self-loop term (already n_d-scaled)
  float dsum = nd;                  // self-loop contribution to A-hat * 1
  for (int j = beg; j < end; ++j) {
    int s = csr_src[j];
    acc += Xs[s*8 + c];
    if (c == 0) dsum += dinv[s];
  }
  Ys[t] = nd * nd * acc;            // = n_d * Y8  (pre-scaled for pass 2)
  if (c == 0) dvec[d] = nd * dsum;
}

// ---------------- gather pass 2: G = n (sum_in Ys + Ys_self) -----------------
__global__ __launch_bounds__(256) void k_gather2(const int* __restrict__ rowptr,
                                                 const int* __restrict__ csr_src,
                                                 const float* __restrict__ dinv,
                                                 const float* __restrict__ Ys,
                                                 float* __restrict__ G) {
  int t = blockIdx.x * 256 + threadIdx.x;
  int d = t >> 3, c = t & 7;
  if (d >= N_NODES) return;
  int beg = rowptr[d], end = rowptr[d + 1];
  float acc = Ys[d*8 + c];          // self-loop
  for (int j = beg; j < end; ++j) {
    int s = csr_src[j];
    acc += Ys[s*8 + c];
  }
  G[t] = dinv[d] * acc;
}

// ---------------- per-node finalize + bank path -> gall [(N+NB),8] ----------
__global__ __launch_bounds__(256) void k_gall(const float* __restrict__ G,
                                              const float* __restrict__ dvec,
                                              const float* __restrict__ bank,
                                              const Consts* __restrict__ cst,
                                              float* __restrict__ gall) {
  int t = blockIdx.x * 256 + threadIdx.x;
  int i = t >> 3, k = t & 7;
  if (i < N_NODES) {
    gall[t] = G[t] + dvec[i] * cst->u[k] + cst->vg[k];
  } else if (i < N_NODES + NB_BANK) {
    int b = i - N_NODES;
    float s = cst->vb[k];
    for (int c = 0; c < 27; ++c) s += bank[b*27+c] * cst->Rb[c*8+k];
    gall[t] = s;
  }
}

// ---------------- float <-> monotone-key helpers for atomic max -------------
__device__ inline unsigned int f2key(float f) {
  int b = __float_as_int(f);
  return (b >= 0) ? ((unsigned)b | 0x80000000u) : ~(unsigned)b;
}
__device__ inline float key2f(unsigned int key) {
  unsigned ub = (key & 0x80000000u) ? (key ^ 0x80000000u) : ~key;
  return __int_as_float((int)ub);
}

// ---------------- pair gather + z + column max -------------------------------
__global__ __launch_bounds__(256) void k_z(const int* __restrict__ node1,
                                           const int* __restrict__ node2,
                                           const float* __restrict__ gall,
                                           float* __restrict__ z,
                                           unsigned int* __restrict__ maxkeys) {
  int p = blockIdx.x * 256 + threadIdx.x;
  float4 zv = make_float4(-1e30f, -1e30f, -1e30f, -1e30f);
  if (p < N_PAIRS) {
    int n1 = node1[p], n2 = node2[p];
    const float4 a = *(const float4*)(gall + n1*8);
    const float4 b = *(const float4*)(gall + n2*8 + 4);
    zv = make_float4(a.x+b.x, a.y+b.y, a.z+b.z, a.w+b.w);
    ((float4*)z)[p] = zv;
  }
  __shared__ float4 sm[256];
  sm[threadIdx.x] = zv;
  __syncthreads();
  for (int s = 128; s > 0; s >>= 1) {
    if (threadIdx.x < s) {
      float4 o = sm[threadIdx.x + s];
      float4 m = sm[threadIdx.x];
      m.x = fmaxf(m.x, o.x); m.y = fmaxf(m.y, o.y);
      m.z = fmaxf(m.z, o.z); m.w = fmaxf(m.w, o.w);
      sm[threadIdx.x] = m;
    }
    __syncthreads();
  }
  if (threadIdx.x < 4) {
    float4 m = sm[0];
    float v = (threadIdx.x == 0) ? m.x : (threadIdx.x == 1) ? m.y
             : (threadIdx.x == 2) ? m.z : m.w;
    atomicMax(&maxkeys[threadIdx.x], f2key(v));
  }
}

// ---------------- sum of exp(z - m) per column -------------------------------
__global__ __launch_bounds__(256) void k_sumexp(const float* __restrict__ z,
                                                const unsigned int* __restrict__ maxkeys,
                                                float* __restrict__ sums) {
  int p = blockIdx.x * 256 + threadIdx.x;
  float m0 = key2f(maxkeys[0]), m1 = key2f(maxkeys[1]);
  float m2 = key2f(maxkeys[2]), m3 = key2f(maxkeys[3]);
  float4 acc = make_float4(0.f, 0.f, 0.f, 0.f);
  if (p < N_PAIRS) {
    float4 zv = ((const float4*)z)[p];
    acc.x = expf(zv.x - m0); acc.y = expf(zv.y - m1);
    acc.z = expf(zv.z - m2); acc.w = expf(zv.w - m3);
  }
  __shared__ float4 sm[256];
  sm[threadIdx.x] = acc;
  __syncthreads();
  for (int s = 128; s > 0; s >>= 1) {
    if (threadIdx.x < s) {
      float4 o = sm[threadIdx.x + s];
      float4 m = sm[threadIdx.x];
      m.x += o.x; m.y += o.y; m.z += o.z; m.w += o.w;
      sm[threadIdx.x] = m;
    }
    __syncthreads();
  }
  if (threadIdx.x < 4) {
    float4 m = sm[0];
    float v = (threadIdx.x == 0) ? m.x : (threadIdx.x == 1) ? m.y
             : (threadIdx.x == 2) ? m.z : m.w;
    atomicAdd(&sums[threadIdx.x], v);
  }
}

// ---------------- normalize --------------------------------------------------
__global__ __launch_bounds__(256) void k_final(const float* __restrict__ z,
                                               const unsigned int* __restrict__ maxkeys,
                                               const float* __restrict__ sums,
                                               float* __restrict__ out) {
  int p = blockIdx.x * 256 + threadIdx.x;
  if (p < N_PAIRS) {
    float m0 = key2f(maxkeys[0]), m1 = key2f(maxkeys[1]);
    float m2 = key2f(maxkeys[2]), m3 = key2f(maxkeys[3]);
    float i0 = 1.f / sums[0], i1 = 1.f / sums[1];
    float i2 = 1.f / sums[2], i3 = 1.f / sums[3];
    float4 zv = ((const float4*)z)[p];
    float4 o = make_float4(expf(zv.x - m0) * i0, expf(zv.y - m1) * i1,
                           expf(zv.z - m2) * i2, expf(zv.w - m3) * i3);
    ((float4*)out)[p] = o;
  }
}

extern "C" void kernel_launch(void* const* d_in, const int* in_sizes, int n_in,
                              void* d_out, int out_size, void* d_ws, size_t ws_size,
                              hipStream_t stream) {
  const float* x    = (const float*)d_in[0];
  const float* bank = (const float*)d_in[1];
  const float* W1   = (const float*)d_in[2];
  const float* b1   = (const float*)d_in[3];
  const float* W2   = (const float*)d_in[4];
  const float* b2   = (const float*)d_in[5];
  const float* Wb   = (const float*)d_in[6];
  const float* bb   = (const float*)d_in[7];
  const float* Wf1  = (const float*)d_in[8];
  const float* bf1  = (const float*)d_in[9];
  const float* Wf2  = (const float*)d_in[10];
  const float* bf2  = (const float*)d_in[11];
  const float* Wf3  = (const float*)d_in[12];
  const float* bf3  = (const float*)d_in[13];
  const int* ei     = (const int*)d_in[14];
  const int* node1  = (const int*)d_in[15];
  const int* node2  = (const int*)d_in[16];
  float* out = (float*)d_out;

  char* w = (char*)d_ws;
  size_t off = 0;
  auto take = [&](size_t bytes) -> char* {
    char* p = w + off;
    off = (off + bytes + 255) & ~(size_t)255;
    return p;
  };
  Consts* cst    = (Consts*)take(sizeof(Consts));
  int*    deg    = (int*)take(N_NODES * 4);
  float*  dinv   = (float*)take(N_NODES * 4);
  int*    rowptr = (int*)take((N_NODES + 1) * 4);
  int*    cursor = (int*)take(N_NODES * 4);
  int*    csr    = (int*)take((size_t)N_EDGES * 4);
  int*    bsum   = (int*)take(NBLK * 4);
  int*    boff   = (int*)take(NBLK * 4);
  float*  Xs     = (float*)take((size_t)N_NODES * 8 * 4);
  float*  Ys     = (float*)take((size_t)N_NODES * 8 * 4);
  float*  dvec   = (float*)take(N_NODES * 4);
  float*  G      = (float*)take((size_t)N_NODES * 8 * 4);
  float*  gall   = (float*)take((size_t)(N_NODES + NB_BANK) * 8 * 4);
  float*  z      = (float*)take((size_t)N_PAIRS * 4 * 4);
  unsigned int* maxkeys = (unsigned int*)take(16);
  float*  sums   = (float*)take(16);

  hipMemsetAsync(deg, 0, N_NODES * 4, stream);
  hipMemsetAsync(maxkeys, 0, 16, stream);
  hipMemsetAsync(sums, 0, 16, stream);

  k_precompute<<<1, 256, 0, stream>>>(W1, b1, W2, b2, Wb, bb,
                                      Wf1, bf1, Wf2, bf2, Wf3, bf3, cst);
  k_deg<<<(N_EDGES + 255) / 256, 256, 0, stream>>>(ei, deg);
  k_dinv<<<(N_NODES + 255) / 256, 256, 0, stream>>>(deg, dinv);
  // CSR build
  k_scan1<<<NBLK, 256, 0, stream>>>(deg, bsum);
  k_scan2<<<1, 512, 0, stream>>>(bsum, boff);
  k_scan3<<<NBLK, 256, 0, stream>>>(deg, boff, rowptr, cursor);
  k_fill<<<(N_EDGES + 255) / 256, 256, 0, stream>>>(ei, cursor, csr);
  // features
  k_x8<<<(N_NODES + 31) / 32, 256, 0, stream>>>(x, dinv, cst, Xs);
  // propagation (atomic-free gathers)
  k_gather1<<<(N_NODES * 8 + 255) / 256, 256, 0, stream>>>(rowptr, csr, dinv, Xs, Ys, dvec);
  k_gather2<<<(N_NODES * 8 + 255) / 256, 256, 0, stream>>>(rowptr, csr, dinv, Ys, G);

  k_gall<<<((N_NODES + NB_BANK) * 8 + 255) / 256, 256, 0, stream>>>(G, dvec, bank, cst, gall);
  k_z<<<(N_PAIRS + 255) / 256, 256, 0, stream>>>(node1, node2, gall, z, maxkeys);
  k_sumexp<<<(N_PAIRS + 255) / 256, 256, 0, stream>>>(z, maxkeys, sums);
  k_final<<<(N_PAIRS + 255) / 256, 256, 0, stream>>>(z, maxkeys, sums, out);
}

// Round 4
// 338.222 us; speedup vs baseline: 1.4659x; 1.2760x over previous
//
#include <hip/hip_runtime.h>
#include <math.h>

#define N_NODES 100000
#define N_EDGES 1600000
#define NB_BANK 1000
#define N_PAIRS 500000
#define NBLK 391                 // ceil(N_NODES/256)
#define BUCK_SHIFT 9
#define BUCK_NODES 512
#define NBUCK ((N_NODES + BUCK_NODES - 1) / BUCK_NODES)   // 196
#define EPB 2048                 // edges per k_bscatter block

struct Consts {
  float C[27*8];    // [P1|P2] : X -> 8 channels
  float Rb[27*8];   // [Wb@Ttop | Wb@Tbot]
  float u[8];       // [b1@W2@Ttop | b1@W2@Tbot]  (coefficient of dvec_i)
  float vg[8];      // [b2@Ttop + c | b2@Tbot]
  float vb[8];      // [bb@Ttop + c | bb@Tbot]
};

// ---------------- tiny dense precompute (all weight-chain products) ----------
__global__ __launch_bounds__(256) void k_precompute(
    const float* __restrict__ W1, const float* __restrict__ b1,
    const float* __restrict__ W2, const float* __restrict__ b2,
    const float* __restrict__ Wb, const float* __restrict__ bb,
    const float* __restrict__ Wf1, const float* __restrict__ bf1,
    const float* __restrict__ Wf2, const float* __restrict__ bf2,
    const float* __restrict__ Wf3, const float* __restrict__ bf3,
    Consts* __restrict__ cst) {
  __shared__ float A[40*4];    // Wf2 @ Wf3
  __shared__ float T[100*4];   // Wf1 @ A
  __shared__ float B[60*8];    // W2 @ [Ttop|Tbot]
  __shared__ float cvec[4];
  const int tid = threadIdx.x;

  for (int idx = tid; idx < 160; idx += 256) {
    int r = idx >> 2, k = idx & 3;
    float s = 0.f;
    for (int j = 0; j < 20; ++j) s += Wf2[r*20+j] * Wf3[j*4+k];
    A[idx] = s;
  }
  __syncthreads();
  for (int idx = tid; idx < 400; idx += 256) {
    int r = idx >> 2, k = idx & 3;
    float s = 0.f;
    for (int j = 0; j < 40; ++j) s += Wf1[r*40+j] * A[j*4+k];
    T[idx] = s;
  }
  if (tid < 4) {
    float s = bf3[tid];
    for (int j = 0; j < 40; ++j) s += bf1[j] * A[j*4+tid];
    for (int j = 0; j < 20; ++j) s += bf2[j] * Wf3[j*4+tid];
    cvec[tid] = s;
  }
  __syncthreads();
  for (int idx = tid; idx < 480; idx += 256) {
    int r = idx >> 3, k = idx & 7;
    int half = k >> 2, kk = k & 3;
    float s = 0.f;
    for (int j = 0; j < 50; ++j) s += W2[r*50+j] * T[(half*50+j)*4+kk];
    B[idx] = s;
  }
  __syncthreads();
  for (int idx = tid; idx < 456; idx += 256) {
    if (idx < 216) {                       // C = W1 @ B [27,8]
      int r = idx >> 3, k = idx & 7;
      float s = 0.f;
      for (int j = 0; j < 60; ++j) s += W1[r*60+j] * B[j*8+k];
      cst->C[idx] = s;
    } else if (idx < 432) {                // Rb = Wb @ [Ttop|Tbot] [27,8]
      int i2 = idx - 216;
      int r = i2 >> 3, k = i2 & 7, half = k >> 2, kk = k & 3;
      float s = 0.f;
      for (int j = 0; j < 50; ++j) s += Wb[r*50+j] * T[(half*50+j)*4+kk];
      cst->Rb[i2] = s;
    } else if (idx < 440) {                // u = b1 @ B
      int k = idx - 432;
      float s = 0.f;
      for (int j = 0; j < 60; ++j) s += b1[j] * B[j*8+k];
      cst->u[k] = s;
    } else if (idx < 448) {                // vg = b2 @ [Ttop|Tbot] (+c on half 0)
      int k = idx - 440, half = k >> 2, kk = k & 3;
      float s = (half == 0) ? cvec[kk] : 0.f;
      for (int j = 0; j < 50; ++j) s += b2[j] * T[(half*50+j)*4+kk];
      cst->vg[k] = s;
    } else {                               // vb = bb @ [Ttop|Tbot] (+c on half 0)
      int k = idx - 448, half = k >> 2, kk = k & 3;
      float s = (half == 0) ? cvec[kk] : 0.f;
      for (int j = 0; j < 50; ++j) s += bb[j] * T[(half*50+j)*4+kk];
      cst->vb[k] = s;
    }
  }
}

// ---------------- degree / dinv ----------------
__global__ __launch_bounds__(256) void k_deg(const int* __restrict__ ei,
                                             int* __restrict__ deg) {
  int e = blockIdx.x * 256 + threadIdx.x;
  if (e < N_EDGES) atomicAdd(&deg[ei[N_EDGES + e]], 1);
}

__global__ __launch_bounds__(256) void k_dinv(const int* __restrict__ deg,
                                              float* __restrict__ dinv) {
  int i = blockIdx.x * 256 + threadIdx.x;
  if (i < N_NODES) dinv[i] = rsqrtf((float)deg[i] + 1.0f);  // +1 self-loop
}

// ---------------- exclusive scan of deg -> rowptr ----------------------------
__global__ __launch_bounds__(256) void k_scan1(const int* __restrict__ deg,
                                               int* __restrict__ blocksum) {
  __shared__ int sm[256];
  int i = blockIdx.x * 256 + threadIdx.x;
  sm[threadIdx.x] = (i < N_NODES) ? deg[i] : 0;
  __syncthreads();
  for (int s = 128; s > 0; s >>= 1) {
    if (threadIdx.x < s) sm[threadIdx.x] += sm[threadIdx.x + s];
    __syncthreads();
  }
  if (threadIdx.x == 0) blocksum[blockIdx.x] = sm[0];
}

__global__ __launch_bounds__(512) void k_scan2(const int* __restrict__ blocksum,
                                               int* __restrict__ blockoff) {
  __shared__ int sm[512];
  int t = threadIdx.x;
  int v = (t < NBLK) ? blocksum[t] : 0;
  sm[t] = v;
  __syncthreads();
  for (int off = 1; off < 512; off <<= 1) {
    int u = (t >= off) ? sm[t - off] : 0;
    __syncthreads();
    sm[t] += u;
    __syncthreads();
  }
  if (t < NBLK) blockoff[t] = sm[t] - v;  // exclusive
}

__global__ __launch_bounds__(256) void k_scan3(const int* __restrict__ deg,
                                               const int* __restrict__ blockoff,
                                               int* __restrict__ rowptr) {
  __shared__ int sm[256];
  int i = blockIdx.x * 256 + threadIdx.x;
  int t = threadIdx.x;
  int v = (i < N_NODES) ? deg[i] : 0;
  sm[t] = v;
  __syncthreads();
  for (int off = 1; off < 256; off <<= 1) {
    int u = (t >= off) ? sm[t - off] : 0;
    __syncthreads();
    sm[t] += u;
    __syncthreads();
  }
  if (i < N_NODES) rowptr[i] = blockoff[blockIdx.x] + sm[t] - v;
  if (i == 0) rowptr[N_NODES] = N_EDGES;
}

// ---------------- bucket cursors = rowptr at bucket starts -------------------
__global__ __launch_bounds__(256) void k_bcur(const int* __restrict__ rowptr,
                                              int* __restrict__ bcursor) {
  int b = blockIdx.x * 256 + threadIdx.x;
  if (b < NBUCK) {
    int n = b << BUCK_SHIFT;
    bcursor[b] = rowptr[n < N_NODES ? n : N_NODES];
  }
}

// ---------------- bucket scatter: ebuf gets (dst,src) grouped by bucket ------
__global__ __launch_bounds__(256) void k_bscatter(const int* __restrict__ ei,
                                                  int* __restrict__ bcursor,
                                                  int2* __restrict__ ebuf) {
  __shared__ int hist[NBUCK];
  __shared__ int base[NBUCK];
  const int t = threadIdx.x;
  const int e0 = blockIdx.x * EPB;
  for (int i = t; i < NBUCK; i += 256) hist[i] = 0;
  __syncthreads();
  for (int i = t; i < EPB; i += 256) {
    int e = e0 + i;
    if (e < N_EDGES) atomicAdd(&hist[ei[N_EDGES + e] >> BUCK_SHIFT], 1);
  }
  __syncthreads();
  for (int i = t; i < NBUCK; i += 256) {
    int h = hist[i];
    base[i] = h ? atomicAdd(&bcursor[i], h) : 0;
  }
  __syncthreads();
  for (int i = t; i < NBUCK; i += 256) hist[i] = 0;
  __syncthreads();
  for (int i = t; i < EPB; i += 256) {
    int e = e0 + i;
    if (e < N_EDGES) {
      int s = ei[e], d = ei[N_EDGES + e];
      int b = d >> BUCK_SHIFT;
      int pos = base[b] + atomicAdd(&hist[b], 1);
      ebuf[pos] = make_int2(d, s);
    }
  }
}

// ---------------- per-bucket CSR fill (LDS cursors, local writes) ------------
__global__ __launch_bounds__(256) void k_bfill(const int* __restrict__ rowptr,
                                               const int2* __restrict__ ebuf,
                                               int* __restrict__ csr) {
  __shared__ int lcur[BUCK_NODES];
  const int b = blockIdx.x;
  const int nbase = b << BUCK_SHIFT;
  const int t = threadIdx.x;
  for (int i = t; i < BUCK_NODES; i += 256) {
    int node = nbase + i;
    lcur[i] = (node < N_NODES) ? rowptr[node] : N_EDGES;
  }
  __syncthreads();
  int nend = nbase + BUCK_NODES; if (nend > N_NODES) nend = N_NODES;
  const int beg = rowptr[nbase];
  const int end = rowptr[nend];
  for (int j = beg + t; j < end; j += 256) {
    int2 e = ebuf[j];
    int pos = atomicAdd(&lcur[e.x - nbase], 1);
    csr[pos] = e.y;
  }
}

// ---------------- Xs = (X @ [P1|P2]) * dinv[i]  ------------------------------
__global__ __launch_bounds__(256) void k_x8(const float* __restrict__ x,
                                            const float* __restrict__ dinv,
                                            const Consts* __restrict__ cst,
                                            float* __restrict__ Xs) {
  __shared__ float xs[32*27];
  const int tid = threadIdx.x;
  const int base = blockIdx.x * 32 * 27;
  for (int j = tid; j < 32*27; j += 256) {
    int g = base + j;
    xs[j] = (g < N_NODES*27) ? x[g] : 0.f;
  }
  __syncthreads();
  int li = tid >> 3, k = tid & 7;
  int node = blockIdx.x * 32 + li;
  if (node < N_NODES) {
    float s = 0.f;
    for (int c = 0; c < 27; ++c) s += xs[li*27+c] * cst->C[c*8+k];
    Xs[node*8+k] = s * dinv[node];
  }
}

// ---------------- gather pass 1: Ys = n^2 (sum_in Xs + Xs_self), dvec --------
__global__ __launch_bounds__(256) void k_gather1(const int* __restrict__ rowptr,
                                                 const int* __restrict__ csr,
                                                 const float* __restrict__ dinv,
                                                 const float* __restrict__ Xs,
                                                 float* __restrict__ Ys,
                                                 float* __restrict__ dvec) {
  int t = blockIdx.x * 256 + threadIdx.x;
  int d = t >> 3, c = t & 7;
  if (d >= N_NODES) return;
  const int beg = rowptr[d], end = rowptr[d + 1];
  const float nd = dinv[d];
  float acc = Xs[d*8 + c];          // self-loop term (already n_d-scaled)
  float dsum = nd;                  // self-loop contribution to A-hat * 1
  int j = beg;
  for (; j + 4 <= end; j += 4) {    // unroll-4: independent load batches
    int s0 = csr[j], s1 = csr[j+1], s2 = csr[j+2], s3 = csr[j+3];
    float a0 = Xs[s0*8+c], a1 = Xs[s1*8+c], a2 = Xs[s2*8+c], a3 = Xs[s3*8+c];
    acc += (a0 + a1) + (a2 + a3);
    if (c == 0) dsum += (dinv[s0] + dinv[s1]) + (dinv[s2] + dinv[s3]);
  }
  for (; j < end; ++j) {
    int s = csr[j];
    acc += Xs[s*8 + c];
    if (c == 0) dsum += dinv[s];
  }
  Ys[t] = nd * nd * acc;            // = n_d * h1  (pre-scaled for pass 2)
  if (c == 0) dvec[d] = nd * dsum;
}

// ---- gather pass 2 fused with finalize + bank path -> gall [(N+NB),8] -------
__global__ __launch_bounds__(256) void k_gather2g(const int* __restrict__ rowptr,
                                                  const int* __restrict__ csr,
                                                  const float* __restrict__ dinv,
                                                  const float* __restrict__ Ys,
                                                  const float* __restrict__ dvec,
                                                  const float* __restrict__ bank,
                                                  const Consts* __restrict__ cst,
                                                  float* __restrict__ gall) {
  int t = blockIdx.x * 256 + threadIdx.x;
  int d = t >> 3, c = t & 7;
  if (d >= N_NODES + NB_BANK) return;
  if (d >= N_NODES) {               // bank rows
    int b = d - N_NODES;
    float s = cst->vb[c];
    for (int cc = 0; cc < 27; ++cc) s += bank[b*27+cc] * cst->Rb[cc*8+c];
    gall[t] = s;
    return;
  }
  const int beg = rowptr[d], end = rowptr[d + 1];
  float acc = Ys[d*8 + c];          // self-loop
  int j = beg;
  for (; j + 4 <= end; j += 4) {
    int s0 = csr[j], s1 = csr[j+1], s2 = csr[j+2], s3 = csr[j+3];
    float a0 = Ys[s0*8+c], a1 = Ys[s1*8+c], a2 = Ys[s2*8+c], a3 = Ys[s3*8+c];
    acc += (a0 + a1) + (a2 + a3);
  }
  for (; j < end; ++j) acc += Ys[csr[j]*8 + c];
  gall[t] = dinv[d] * acc + dvec[d] * cst->u[c] + cst->vg[c];
}

// ---------------- float <-> monotone-key helpers for atomic max -------------
__device__ inline unsigned int f2key(float f) {
  int b = __float_as_int(f);
  return (b >= 0) ? ((unsigned)b | 0x80000000u) : ~(unsigned)b;
}
__device__ inline float key2f(unsigned int key) {
  unsigned ub = (key & 0x80000000u) ? (key ^ 0x80000000u) : ~key;
  return __int_as_float((int)ub);
}

// ---------------- pair gather + z + column max -------------------------------
__global__ __launch_bounds__(256) void k_z(const int* __restrict__ node1,
                                           const int* __restrict__ node2,
                                           const float* __restrict__ gall,
                                           float* __restrict__ z,
                                           unsigned int* __restrict__ maxkeys) {
  int p = blockIdx.x * 256 + threadIdx.x;
  float4 zv = make_float4(-1e30f, -1e30f, -1e30f, -1e30f);
  if (p < N_PAIRS) {
    int n1 = node1[p], n2 = node2[p];
    const float4 a = *(const float4*)(gall + n1*8);
    const float4 b = *(const float4*)(gall + n2*8 + 4);
    zv = make_float4(a.x+b.x, a.y+b.y, a.z+b.z, a.w+b.w);
    ((float4*)z)[p] = zv;
  }
  __shared__ float4 sm[256];
  sm[threadIdx.x] = zv;
  __syncthreads();
  for (int s = 128; s > 0; s >>= 1) {
    if (threadIdx.x < s) {
      float4 o = sm[threadIdx.x + s];
      float4 m = sm[threadIdx.x];
      m.x = fmaxf(m.x, o.x); m.y = fmaxf(m.y, o.y);
      m.z = fmaxf(m.z, o.z); m.w = fmaxf(m.w, o.w);
      sm[threadIdx.x] = m;
    }
    __syncthreads();
  }
  if (threadIdx.x < 4) {
    float4 m = sm[0];
    float v = (threadIdx.x == 0) ? m.x : (threadIdx.x == 1) ? m.y
             : (threadIdx.x == 2) ? m.z : m.w;
    atomicMax(&maxkeys[threadIdx.x], f2key(v));
  }
}

// ---------------- sum of exp(z - m) per column -------------------------------
__global__ __launch_bounds__(256) void k_sumexp(const float* __restrict__ z,
                                                const unsigned int* __restrict__ maxkeys,
                                                float* __restrict__ sums) {
  int p = blockIdx.x * 256 + threadIdx.x;
  float m0 = key2f(maxkeys[0]), m1 = key2f(maxkeys[1]);
  float m2 = key2f(maxkeys[2]), m3 = key2f(maxkeys[3]);
  float4 acc = make_float4(0.f, 0.f, 0.f, 0.f);
  if (p < N_PAIRS) {
    float4 zv = ((const float4*)z)[p];
    acc.x = expf(zv.x - m0); acc.y = expf(zv.y - m1);
    acc.z = expf(zv.z - m2); acc.w = expf(zv.w - m3);
  }
  __shared__ float4 sm[256];
  sm[threadIdx.x] = acc;
  __syncthreads();
  for (int s = 128; s > 0; s >>= 1) {
    if (threadIdx.x < s) {
      float4 o = sm[threadIdx.x + s];
      float4 m = sm[threadIdx.x];
      m.x += o.x; m.y += o.y; m.z += o.z; m.w += o.w;
      sm[threadIdx.x] = m;
    }
    __syncthreads();
  }
  if (threadIdx.x < 4) {
    float4 m = sm[0];
    float v = (threadIdx.x == 0) ? m.x : (threadIdx.x == 1) ? m.y
             : (threadIdx.x == 2) ? m.z : m.w;
    atomicAdd(&sums[threadIdx.x], v);
  }
}

// ---------------- normalize --------------------------------------------------
__global__ __launch_bounds__(256) void k_final(const float* __restrict__ z,
                                               const unsigned int* __restrict__ maxkeys,
                                               const float* __restrict__ sums,
                                               float* __restrict__ out) {
  int p = blockIdx.x * 256 + threadIdx.x;
  if (p < N_PAIRS) {
    float m0 = key2f(maxkeys[0]), m1 = key2f(maxkeys[1]);
    float m2 = key2f(maxkeys[2]), m3 = key2f(maxkeys[3]);
    float i0 = 1.f / sums[0], i1 = 1.f / sums[1];
    float i2 = 1.f / sums[2], i3 = 1.f / sums[3];
    float4 zv = ((const float4*)z)[p];
    float4 o = make_float4(expf(zv.x - m0) * i0, expf(zv.y - m1) * i1,
                           expf(zv.z - m2) * i2, expf(zv.w - m3) * i3);
    ((float4*)out)[p] = o;
  }
}

extern "C" void kernel_launch(void* const* d_in, const int* in_sizes, int n_in,
                              void* d_out, int out_size, void* d_ws, size_t ws_size,
                              hipStream_t stream) {
  const float* x    = (const float*)d_in[0];
  const float* bank = (const float*)d_in[1];
  const float* W1   = (const float*)d_in[2];
  const float* b1   = (const float*)d_in[3];
  const float* W2   = (const float*)d_in[4];
  const float* b2   = (const float*)d_in[5];
  const float* Wb   = (const float*)d_in[6];
  const float* bb   = (const float*)d_in[7];
  const float* Wf1  = (const float*)d_in[8];
  const float* bf1  = (const float*)d_in[9];
  const float* Wf2  = (const float*)d_in[10];
  const float* bf2  = (const float*)d_in[11];
  const float* Wf3  = (const float*)d_in[12];
  const float* bf3  = (const float*)d_in[13];
  const int* ei     = (const int*)d_in[14];
  const int* node1  = (const int*)d_in[15];
  const int* node2  = (const int*)d_in[16];
  float* out = (float*)d_out;

  char* w = (char*)d_ws;
  size_t off = 0;
  auto take = [&](size_t bytes) -> char* {
    char* p = w + off;
    off = (off + bytes + 255) & ~(size_t)255;
    return p;
  };
  Consts* cst    = (Consts*)take(sizeof(Consts));
  int*    deg    = (int*)take(N_NODES * 4);
  float*  dinv   = (float*)take(N_NODES * 4);
  int*    rowptr = (int*)take((N_NODES + 1) * 4);
  int*    bcursor= (int*)take(NBUCK * 4);
  int*    csr    = (int*)take((size_t)N_EDGES * 4);
  int*    bsum   = (int*)take(NBLK * 4);
  int*    boff   = (int*)take(NBLK * 4);
  float*  Xs     = (float*)take((size_t)N_NODES * 8 * 4);
  float*  Ys     = (float*)take((size_t)N_NODES * 8 * 4);
  float*  dvec   = (float*)take(N_NODES * 4);
  float*  gall   = (float*)take((size_t)(N_NODES + NB_BANK) * 8 * 4);
  // ebuf (E * 8B, build phase) and z (P * 16B, pair phase) have disjoint
  // lifetimes -> share one region.
  char*   shreg  = take((size_t)N_EDGES * 8);
  int2*   ebuf   = (int2*)shreg;
  float*  z      = (float*)shreg;
  unsigned int* maxkeys = (unsigned int*)take(16);
  float*  sums   = (float*)take(16);

  hipMemsetAsync(deg, 0, N_NODES * 4, stream);
  hipMemsetAsync(maxkeys, 0, 16, stream);
  hipMemsetAsync(sums, 0, 16, stream);

  k_precompute<<<1, 256, 0, stream>>>(W1, b1, W2, b2, Wb, bb,
                                      Wf1, bf1, Wf2, bf2, Wf3, bf3, cst);
  k_deg<<<(N_EDGES + 255) / 256, 256, 0, stream>>>(ei, deg);
  k_dinv<<<(N_NODES + 255) / 256, 256, 0, stream>>>(deg, dinv);
  // rowptr scan
  k_scan1<<<NBLK, 256, 0, stream>>>(deg, bsum);
  k_scan2<<<1, 512, 0, stream>>>(bsum, boff);
  k_scan3<<<NBLK, 256, 0, stream>>>(deg, boff, rowptr);
  // bucketed CSR build
  k_bcur<<<1, 256, 0, stream>>>(rowptr, bcursor);
  k_bscatter<<<(N_EDGES + EPB - 1) / EPB, 256, 0, stream>>>(ei, bcursor, ebuf);
  k_bfill<<<NBUCK, 256, 0, stream>>>(rowptr, ebuf, csr);
  // features
  k_x8<<<(N_NODES + 31) / 32, 256, 0, stream>>>(x, dinv, cst, Xs);
  // propagation (atomic-free gathers, unroll-4)
  k_gather1<<<(N_NODES * 8 + 255) / 256, 256, 0, stream>>>(rowptr, csr, dinv, Xs, Ys, dvec);
  k_gather2g<<<((N_NODES + NB_BANK) * 8 + 255) / 256, 256, 0, stream>>>(
      rowptr, csr, dinv, Ys, dvec, bank, cst, gall);
  // pair phase
  k_z<<<(N_PAIRS + 255) / 256, 256, 0, stream>>>(node1, node2, gall, z, maxkeys);
  k_sumexp<<<(N_PAIRS + 255) / 256, 256, 0, stream>>>(z, maxkeys, sums);
  k_final<<<(N_PAIRS + 255) / 256, 256, 0, stream>>>(z, maxkeys, sums, out);
}